// Round 9
// baseline (42.723 us; speedup 1.0000x reference)
//
#include <hip/hip_runtime.h>
#include <hip/hip_fp16.h>

#define MROWS 512
#define NCOLS 8192
#define NVALS 4096
#define BLOCK 512
#define NW 8
#define EPSF 1e-10f

typedef unsigned int u32;
typedef unsigned short u16;

// transposed layout: thread t owns logical e=8t..8t+7 at phys (i<<9)+t (conflict-free)
__device__ __forceinline__ int TP(int e) { return ((e & 7) << 9) | (e >> 3); }
__device__ __forceinline__ u16 f2h(float x) { return __half_as_ushort(__float2half_rn(x)); }
__device__ __forceinline__ float h2f(u16 h) { return __half2float(__ushort_as_half(h)); }

__global__ __launch_bounds__(BLOCK, 4) void listmle_row_kernel(
    const float* __restrict__ outputs,
    const float* __restrict__ runtime,
    const int*   __restrict__ idxs,
    float* __restrict__ row_out)
{
    // 16 + 16 + 8 KB + scratch = 40.3 KB
    __shared__ u32 A[NVALS];      // minidx -> bucket bases -> cursors -> bucket ends
    __shared__ u32 KEY[NVALS];    // bucket counts (TP) -> compare keys (linear by pos)
    __shared__ u16 EXPH[NVALS];   // fp16 exp values (linear by pos)
    __shared__ float s_max[NW], s_ps[NW], s_fs[NW];
    __shared__ double s_lg[NW];
    __shared__ u32 s_cnt[NW];

    const int tid = threadIdx.x, lane = tid & 63, wave = tid >> 6;
    const int row = blockIdx.x;
    const float* rp = outputs + (size_t)row * NCOLS;
    const float* rr = runtime + (size_t)row * NCOLS;
    const int*   ri = idxs    + (size_t)row * NCOLS;

    // ---- P0: load 16 items/thread; column j(m) = (m>>2)*2048 + tid*4 + (m&3) ----
    u32 pidx[8]; u32 vkey[16]; float vpred[16];
    #pragma unroll
    for (int q = 0; q < 4; ++q) {
        const int b0 = (q << 11) + (tid << 2);
        const int4   i4 = *reinterpret_cast<const int4*>(ri + b0);
        const float4 r4 = *reinterpret_cast<const float4*>(rr + b0);
        const float4 p4 = *reinterpret_cast<const float4*>(rp + b0);
        pidx[q*2]   = ((u32)i4.x & 0xFFFFu) | ((u32)i4.y << 16);
        pidx[q*2+1] = ((u32)i4.z & 0xFFFFu) | ((u32)i4.w << 16);
        const float rv[4] = { r4.x, r4.y, r4.z, r4.w };
        #pragma unroll
        for (int r = 0; r < 4; ++r) {
            u32 u = (u32)(rv[r] * 16777216.0f);         // exact monotone 24-bit key
            vkey[q*4+r] = u > 0xFFFFFFu ? 0xFFFFFFu : u;
        }
        vpred[q*4+0]=p4.x; vpred[q*4+1]=p4.y; vpred[q*4+2]=p4.z; vpred[q*4+3]=p4.w;
    }
    #pragma unroll
    for (int i = 0; i < 8; ++i) { A[(i<<9)+tid] = 0xFFFFFFFFu; KEY[(i<<9)+tid] = 0u; }
    __syncthreads();                                    // B1

    // ---- P1: dedup — first occurrence (min column) per value ----
    #pragma unroll
    for (int m = 0; m < 16; ++m) {
        const u32 v = (pidx[m>>1] >> ((m & 1) << 4)) & 0xFFFFu;
        const u32 j = ((m >> 2) << 11) + (tid << 2) + (m & 3);
        atomicMin(&A[v], j);
    }
    __syncthreads();                                    // B2

    // ---- P2: kept mask; bucket counts into KEY; max of all preds; sum of kept preds ----
    float lmax = -INFINITY, psum = 0.f;
    u32 kept = 0;
    #pragma unroll
    for (int m = 0; m < 16; ++m) {
        lmax = fmaxf(lmax, vpred[m]);
        const u32 v = (pidx[m>>1] >> ((m & 1) << 4)) & 0xFFFFu;
        const u32 j = ((m >> 2) << 11) + (tid << 2) + (m & 3);
        if (A[v] == j) {
            kept |= 1u << m;
            psum += vpred[m];
            atomicAdd(&KEY[TP((int)(vkey[m] >> 12))], 1u);
        }
    }
    #pragma unroll
    for (int off = 32; off > 0; off >>= 1) {
        lmax = fmaxf(lmax, __shfl_down(lmax, off));
        psum += __shfl_down(psum, off);
    }
    if (lane == 0) { s_max[wave] = lmax; s_ps[wave] = psum; }
    __syncthreads();                                    // B3 (minidx reads + counts done)

    float mx = s_max[0];
    #pragma unroll
    for (int w = 1; w < NW; ++w) mx = fmaxf(mx, s_max[w]);

    // ---- P3: exclusive scan of 4096 bucket counts (8/thread, TP layout) ----
    u32 c8[8], lsum = 0;
    #pragma unroll
    for (int i = 0; i < 8; ++i) { c8[i] = KEY[(i<<9)+tid]; lsum += c8[i]; }
    u32 xs = lsum;
    #pragma unroll
    for (int off = 1; off < 64; off <<= 1) { u32 y = __shfl_up(xs, off); if (lane >= off) xs += y; }
    if (lane == 63) s_cnt[wave] = xs;
    __syncthreads();                                    // B4

    u32 run = xs - lsum, K = 0;
    #pragma unroll
    for (int w = 0; w < NW; ++w) { const u32 t = s_cnt[w]; if (w < wave) run += t; K += t; }
    #pragma unroll
    for (int i = 0; i < 8; ++i) { const u32 c = c8[i]; A[(i<<9)+tid] = run; run += c; }
    __syncthreads();                                    // B5 (bases in A; KEY count slots now dead)

    // ---- P5: scatter (cmpkey, fp16 exp) by atomic arrival; cursor IS the base array ----
    #pragma unroll
    for (int m = 0; m < 16; ++m) {
        if (kept & (1u << m)) {
            const u32 j = ((m >> 2) << 11) + (tid << 2) + (m & 3);
            const u32 k = vkey[m];
            const u32 pos = atomicAdd(&A[TP((int)(k >> 12))], 1u);
            KEY[pos]  = ((k & 0xFFFu) << 13) | j;       // unique: (low12, column<13b)
            EXPH[pos] = f2h(__expf(vpred[m] - mx));
        }
    }
    __syncthreads();                                    // B6 (A[b] = end of bucket b; A frozen)

    // ---- P6a: owner bounds + bucket totals (double accum over fp16 = exact, order-independent) ----
    u32 e8[8]; float f8[8];
    const u32 s0 = (tid == 0) ? 0u : A[TP(8 * tid - 1)];
    {
        u32 st = s0;
        #pragma unroll
        for (int i = 0; i < 8; ++i) {
            const u32 end = A[(i<<9)+tid];              // = A[TP(8*tid+i)]
            e8[i] = end;
            double ds = 0.0;
            for (u32 q = st; q < end; ++q) ds += (double)h2f(EXPH[q]);
            f8[i] = (float)ds;
            st = end;
        }
    }
    // block exclusive scan of the 4096 bucket totals (in registers + one LDS handoff)
    float fsum = 0.f;
    #pragma unroll
    for (int i = 0; i < 8; ++i) fsum += f8[i];
    float xf = fsum;
    #pragma unroll
    for (int off = 1; off < 64; off <<= 1) { const float y = __shfl_up(xf, off); if (lane >= off) xf += y; }
    if (lane == 63) s_fs[wave] = xf;
    __syncthreads();                                    // B7

    float Tx = xf - fsum;                               // exclusive base for bucket 8*tid
    #pragma unroll
    for (int w = 0; w < NW; ++w) if (w < wave) Tx += s_fs[w];

    // ---- P6b: owner computes per-item within-bucket prefix + log (O(c^2), c~0.86 avg) ----
    double logacc = 0.0;
    {
        u32 st = s0;
        #pragma unroll
        for (int i = 0; i < 8; ++i) {
            const u32 end = e8[i];
            for (u32 q = st; q < end; ++q) {
                const u32 kq = KEY[q];
                double dsm = 0.0;
                for (u32 q2 = st; q2 < end; ++q2) {
                    if (KEY[q2] <= kq) dsm += (double)h2f(EXPH[q2]);  // smaller keys + self
                }
                logacc += (double)__logf((float)((double)Tx + dsm) + EPSF);
            }
            Tx += f8[i];
            st = end;
        }
    }
    #pragma unroll
    for (int off = 32; off > 0; off >>= 1) logacc += __shfl_down(logacc, off);
    if (lane == 0) s_lg[wave] = logacc;
    __syncthreads();                                    // B8

    if (tid == 0) {
        double lt = 0.0; float pt = 0.f;
        #pragma unroll
        for (int w = 0; w < NW; ++w) { lt += s_lg[w]; pt += s_ps[w]; }
        row_out[row] = (float)(lt - (double)pt + (double)((float)K * mx));
    }
}

__global__ __launch_bounds__(256) void listmle_finalize(
    const float* __restrict__ row_out, float* __restrict__ out)
{
    __shared__ double red_d[4];
    const int tid = threadIdx.x;
    const int lane = tid & 63, wave = tid >> 6;
    double acc = 0.0;
    for (int r = tid; r < MROWS; r += 256) acc += (double)row_out[r];
    #pragma unroll
    for (int off = 32; off > 0; off >>= 1) acc += __shfl_down(acc, off);
    if (lane == 0) red_d[wave] = acc;
    __syncthreads();
    if (tid == 0) {
        double tot = 0.0;
        for (int w = 0; w < 4; ++w) tot += red_d[w];
        out[0] = (float)(tot / (double)MROWS);
    }
}

extern "C" void kernel_launch(void* const* d_in, const int* in_sizes, int n_in,
                              void* d_out, int out_size, void* d_ws, size_t ws_size,
                              hipStream_t stream) {
    const float* outputs = (const float*)d_in[0];
    const float* runtime = (const float*)d_in[1];
    const int*   idxs    = (const int*)d_in[2];
    float* out = (float*)d_out;
    float* ws  = (float*)d_ws;

    listmle_row_kernel<<<MROWS, BLOCK, 0, stream>>>(outputs, runtime, idxs, ws);
    listmle_finalize<<<1, 256, 0, stream>>>(ws, out);
}

// Round 10
// 27.182 us; speedup vs baseline: 1.5717x; 1.5717x over previous
//
#include <hip/hip_runtime.h>
#include <hip/hip_fp16.h>

#define MROWS 512
#define NCOLS 8192
#define NVALS 4096
#define BLOCK 512
#define NW 8
#define EPSF 1e-10f

typedef unsigned int u32;
typedef unsigned long long u64;
typedef unsigned short u16;

// transposed layout: thread t owns logical e=8t..8t+7 at phys (i<<9)+t (conflict-free)
__device__ __forceinline__ int TP(int e) { return ((e & 7) << 9) | (e >> 3); }
__device__ __forceinline__ u16 f2h(float x) { return __half_as_ushort(__float2half_rn(x)); }
__device__ __forceinline__ float h2f(u16 h) { return __half2float(__ushort_as_half(h)); }

__global__ __launch_bounds__(BLOCK, 4) void listmle_row_kernel(
    const float* __restrict__ outputs,
    const float* __restrict__ runtime,
    const int*   __restrict__ idxs,
    float* __restrict__ row_out)
{
    // 32 + 16 KB + scratch = 48.2 KB
    __shared__ u64 B[NVALS];   // dedup-min (j13|rt24|pred16) -> scatter entries (ck25<<16|exph16)
    __shared__ u32 A[NVALS];   // zeros -> bucket counts -> bases -> ends -> excl sums (TP layout)
    __shared__ float s_max[NW], s_ps[NW], s_fs[NW];
    __shared__ double s_lg[NW];
    __shared__ u32 s_cnt[NW];

    const int tid = threadIdx.x, lane = tid & 63, wave = tid >> 6;
    const int row = blockIdx.x;
    const float* rp = outputs + (size_t)row * NCOLS;
    const float* rr = runtime + (size_t)row * NCOLS;
    const int*   ri = idxs    + (size_t)row * NCOLS;

    // ---- P0: load 16 items/thread; pack pk = (j<<40)|(rt24<<16)|pred_f16; lmax; init ----
    u64 pk[16]; u32 pidx[8];
    float lmax = -INFINITY;
    #pragma unroll
    for (int q = 0; q < 4; ++q) {
        const int b0 = (q << 11) + (tid << 2);
        const int4   i4 = *reinterpret_cast<const int4*>(ri + b0);
        const float4 r4 = *reinterpret_cast<const float4*>(rr + b0);
        const float4 p4 = *reinterpret_cast<const float4*>(rp + b0);
        pidx[q*2]   = ((u32)i4.x & 0xFFFFu) | ((u32)i4.y << 16);
        pidx[q*2+1] = ((u32)i4.z & 0xFFFFu) | ((u32)i4.w << 16);
        const float rv[4] = { r4.x, r4.y, r4.z, r4.w };
        const float pv[4] = { p4.x, p4.y, p4.z, p4.w };
        #pragma unroll
        for (int r = 0; r < 4; ++r) {
            const int m = q*4 + r;
            u32 u = (u32)(rv[r] * 16777216.0f);          // exact monotone 24-bit key
            u = u > 0xFFFFFFu ? 0xFFFFFFu : u;
            const u32 j = (u32)b0 + (u32)r;
            pk[m] = ((u64)j << 40) | ((u64)u << 16) | (u64)f2h(pv[r]);
            lmax = fmaxf(lmax, pv[r]);
        }
    }
    #pragma unroll
    for (int off = 32; off > 0; off >>= 1) lmax = fmaxf(lmax, __shfl_down(lmax, off));
    if (lane == 0) s_max[wave] = lmax;
    #pragma unroll
    for (int i = 0; i < 8; ++i) { B[(i<<9)+tid] = ~0ull; A[(i<<9)+tid] = 0u; }
    __syncthreads();                                    // B1

    // ---- P1: dedup + payload delivery in ONE pass: min over j carries (rt24, pred16) ----
    #pragma unroll
    for (int m = 0; m < 16; ++m) {
        const u32 v = (pidx[m>>1] >> ((m & 1) << 4)) & 0xFFFFu;
        atomicMin(&B[TP((int)v)], pk[m]);
    }
    __syncthreads();                                    // B2

    float mx = s_max[0];
    #pragma unroll
    for (int w = 1; w < NW; ++w) mx = fmaxf(mx, s_max[w]);

    // ---- P2: value-owner extracts 8 slots (conflict-free b64); psum; bucket counts ----
    u64 own[8]; u32 keptmask = 0;
    float psum = 0.f;
    #pragma unroll
    for (int i = 0; i < 8; ++i) {
        const u64 x = B[(i<<9)+tid];                    // = B[TP(8*tid+i)]
        own[i] = x;
        if (x != ~0ull) {
            keptmask |= 1u << i;
            psum += h2f((u16)(x & 0xFFFFu));
            atomicAdd(&A[TP((int)((x >> 28) & 0xFFFu))], 1u);
        }
    }
    #pragma unroll
    for (int off = 32; off > 0; off >>= 1) psum += __shfl_down(psum, off);
    if (lane == 0) s_ps[wave] = psum;
    __syncthreads();                                    // B3 (all extracts + counts done)

    // ---- P3: exclusive scan of 4096 bucket counts (8/thread, TP, in-place) ----
    u32 c8[8], lsum = 0;
    #pragma unroll
    for (int i = 0; i < 8; ++i) { c8[i] = A[(i<<9)+tid]; lsum += c8[i]; }
    u32 xs = lsum;
    #pragma unroll
    for (int off = 1; off < 64; off <<= 1) { u32 y = __shfl_up(xs, off); if (lane >= off) xs += y; }
    if (lane == 63) s_cnt[wave] = xs;
    __syncthreads();                                    // B4

    u32 run = xs - lsum, K = 0;
    #pragma unroll
    for (int w = 0; w < NW; ++w) { const u32 t = s_cnt[w]; if (w < wave) run += t; K += t; }
    #pragma unroll
    for (int i = 0; i < 8; ++i) { const u32 c = c8[i]; A[(i<<9)+tid] = run; run += c; }
    __syncthreads();                                    // B5 (bases in A)

    // ---- P5: scatter packed entries (ck25<<16 | exph16) into B[0..K) by atomic arrival ----
    #pragma unroll
    for (int i = 0; i < 8; ++i) {
        if (keptmask & (1u << i)) {
            const u64 x = own[i];
            const u32 rt24 = (u32)((x >> 16) & 0xFFFFFFu);
            const u32 j    = (u32)((x >> 40) & 0x1FFFu);
            const u32 pos  = atomicAdd(&A[TP((int)(rt24 >> 12))], 1u);
            const u32 ck   = ((rt24 & 0xFFFu) << 13) | j;    // unique within bucket
            const float e  = __expf(h2f((u16)(x & 0xFFFFu)) - mx);
            B[pos] = ((u64)ck << 16) | (u64)f2h(e);
        }
    }
    __syncthreads();                                    // B6 (A[b]=end of bucket b; frozen)

    // ---- P6: per-item within-bucket inclusive prefix (double = exact over fp16);
    //          plus bucket-owner totals f8[8] from its contiguous entry span ----
    float pf[8];
    #pragma unroll
    for (int i = 0; i < 8; ++i) {
        if (keptmask & (1u << i)) {
            const u64 x = own[i];
            const u32 rt24 = (u32)((x >> 16) & 0xFFFFFFu);
            const u32 j    = (u32)((x >> 40) & 0x1FFFu);
            const int b    = (int)(rt24 >> 12);
            const u32 start = b ? A[TP(b - 1)] : 0u;
            const u32 end   = A[TP(b)];
            const u32 ck    = ((rt24 & 0xFFFu) << 13) | j;
            double dsm = 0.0;
            for (u32 q = start; q < end; ++q) {
                const u64 v = B[q];
                if ((u32)(v >> 16) <= ck) dsm += (double)h2f((u16)(v & 0xFFFFu));
            }
            pf[i] = (float)dsm;                          // inclusive (own term via ==)
        }
    }
    float f8[8];
    {
        u32 st = tid ? A[TP(8 * tid - 1)] : 0u;
        #pragma unroll
        for (int i = 0; i < 8; ++i) {
            const u32 end = A[(i<<9)+tid];               // = A[TP(8*tid+i)]
            double ds = 0.0;
            for (u32 q = st; q < end; ++q) ds += (double)h2f((u16)(B[q] & 0xFFFFu));
            f8[i] = (float)ds;
            st = end;
        }
    }
    float fsum = 0.f;
    #pragma unroll
    for (int i = 0; i < 8; ++i) fsum += f8[i];
    float xf = fsum;
    #pragma unroll
    for (int off = 1; off < 64; off <<= 1) { const float y = __shfl_up(xf, off); if (lane >= off) xf += y; }
    if (lane == 63) s_fs[wave] = xf;
    __syncthreads();                                    // B7 (all A/B reads done)

    // ---- P7: bucket-owner writes exclusive global bucket sums into A ----
    float Tx = xf - fsum;
    #pragma unroll
    for (int w = 0; w < NW; ++w) if (w < wave) Tx += s_fs[w];
    #pragma unroll
    for (int i = 0; i < 8; ++i) { A[(i<<9)+tid] = __float_as_uint(Tx); Tx += f8[i]; }
    __syncthreads();                                    // B8

    // ---- P9: logs ----
    double logacc = 0.0;
    #pragma unroll
    for (int i = 0; i < 8; ++i) {
        if (keptmask & (1u << i)) {
            const int b = (int)((own[i] >> 28) & 0xFFFu);
            const float S = __uint_as_float(A[TP(b)]);
            logacc += (double)__logf(S + pf[i] + EPSF);
        }
    }
    #pragma unroll
    for (int off = 32; off > 0; off >>= 1) logacc += __shfl_down(logacc, off);
    if (lane == 0) s_lg[wave] = logacc;
    __syncthreads();                                    // B9

    if (tid == 0) {
        double lt = 0.0; float pt = 0.f;
        #pragma unroll
        for (int w = 0; w < NW; ++w) { lt += s_lg[w]; pt += s_ps[w]; }
        row_out[row] = (float)(lt - (double)pt + (double)((float)K * mx));
    }
}

__global__ __launch_bounds__(256) void listmle_finalize(
    const float* __restrict__ row_out, float* __restrict__ out)
{
    __shared__ double red_d[4];
    const int tid = threadIdx.x;
    const int lane = tid & 63, wave = tid >> 6;
    double acc = 0.0;
    for (int r = tid; r < MROWS; r += 256) acc += (double)row_out[r];
    #pragma unroll
    for (int off = 32; off > 0; off >>= 1) acc += __shfl_down(acc, off);
    if (lane == 0) red_d[wave] = acc;
    __syncthreads();
    if (tid == 0) {
        double tot = 0.0;
        for (int w = 0; w < 4; ++w) tot += red_d[w];
        out[0] = (float)(tot / (double)MROWS);
    }
}

extern "C" void kernel_launch(void* const* d_in, const int* in_sizes, int n_in,
                              void* d_out, int out_size, void* d_ws, size_t ws_size,
                              hipStream_t stream) {
    const float* outputs = (const float*)d_in[0];
    const float* runtime = (const float*)d_in[1];
    const int*   idxs    = (const int*)d_in[2];
    float* out = (float*)d_out;
    float* ws  = (float*)d_ws;

    listmle_row_kernel<<<MROWS, BLOCK, 0, stream>>>(outputs, runtime, idxs, ws);
    listmle_finalize<<<1, 256, 0, stream>>>(ws, out);
}

// Round 11
// 26.862 us; speedup vs baseline: 1.5904x; 1.0119x over previous
//
#include <hip/hip_runtime.h>
#include <hip/hip_fp16.h>

#define MROWS 512
#define NCOLS 8192
#define NVALS 4096
#define BLOCK 512
#define NW 8
#define EPSF 1e-10f

typedef unsigned int u32;
typedef unsigned long long u64;
typedef unsigned short u16;

#define TOTMASK ((1ull << 44) - 1ull)
#define FXSCALE 1073741824.0f   // 2^30

// transposed layout: thread t owns logical e=8t..8t+7 at phys (i<<9)+t (conflict-free)
__device__ __forceinline__ int TP(int e) { return ((e & 7) << 9) | (e >> 3); }
__device__ __forceinline__ u16 f2h(float x) { return __half_as_ushort(__float2half_rn(x)); }
__device__ __forceinline__ float h2f(u16 h) { return __half2float(__ushort_as_half(h)); }

__global__ __launch_bounds__(BLOCK, 2) void listmle_row_kernel(
    const float* __restrict__ outputs,
    const float* __restrict__ runtime,
    const int*   __restrict__ idxs,
    float* __restrict__ row_out)
{
    // 32 + 32 KB + scratch = 64.3 KB -> 2 blocks/CU (grid caps at 2 anyway)
    __shared__ u64 B[NVALS];   // dedup-min (j13|rt24|pred16) -> entries (rt24|j13|exph16) @ TP(pos)
    __shared__ u64 D[NVALS];   // packed (cnt<<44 | tot2^30): per-bucket counts+totals (TP layout)
                               // after scan: reused as two u32[4096]: cursors/ends + S_f32
    __shared__ u64 s_sc[NW];
    __shared__ float s_max[NW], s_ps[NW];
    __shared__ double s_lg[NW];

    u32* Cc = reinterpret_cast<u32*>(D);           // cursor/ends, u32 index [0,4096) (TP)
    u32* Sf = reinterpret_cast<u32*>(D) + NVALS;   // S_excl f32 bits, u32 index [0,4096) (TP)

    const int tid = threadIdx.x, lane = tid & 63, wave = tid >> 6;
    const int row = blockIdx.x;
    const float* rp = outputs + (size_t)row * NCOLS;
    const float* rr = runtime + (size_t)row * NCOLS;
    const int*   ri = idxs    + (size_t)row * NCOLS;

    // ---- P0: load 16 items/thread; pack pk = (j<<40)|(rt24<<16)|pred_f16; lmax; init ----
    u64 pk[16]; u32 pidx[8];
    float lmax = -INFINITY;
    #pragma unroll
    for (int q = 0; q < 4; ++q) {
        const int b0 = (q << 11) + (tid << 2);
        const int4   i4 = *reinterpret_cast<const int4*>(ri + b0);
        const float4 r4 = *reinterpret_cast<const float4*>(rr + b0);
        const float4 p4 = *reinterpret_cast<const float4*>(rp + b0);
        pidx[q*2]   = ((u32)i4.x & 0xFFFFu) | ((u32)i4.y << 16);
        pidx[q*2+1] = ((u32)i4.z & 0xFFFFu) | ((u32)i4.w << 16);
        const float rv[4] = { r4.x, r4.y, r4.z, r4.w };
        const float pv[4] = { p4.x, p4.y, p4.z, p4.w };
        #pragma unroll
        for (int r = 0; r < 4; ++r) {
            u32 u = (u32)(rv[r] * 16777216.0f);          // exact monotone 24-bit key
            u = u > 0xFFFFFFu ? 0xFFFFFFu : u;
            const u32 j = (u32)b0 + (u32)r;
            pk[q*4+r] = ((u64)j << 40) | ((u64)u << 16) | (u64)f2h(pv[r]);
            lmax = fmaxf(lmax, pv[r]);
        }
    }
    #pragma unroll
    for (int off = 32; off > 0; off >>= 1) lmax = fmaxf(lmax, __shfl_down(lmax, off));
    if (lane == 0) s_max[wave] = lmax;
    #pragma unroll
    for (int i = 0; i < 8; ++i) { B[(i<<9)+tid] = ~0ull; D[(i<<9)+tid] = 0ull; }
    __syncthreads();                                    // B1

    // ---- P1: dedup + payload in ONE pass: min over j carries (rt24, pred16) ----
    #pragma unroll
    for (int m = 0; m < 16; ++m) {
        const u32 v = (pidx[m>>1] >> ((m & 1) << 4)) & 0xFFFFu;
        atomicMin(&B[TP((int)v)], pk[m]);
    }
    __syncthreads();                                    // B2

    float mx = s_max[0];
    #pragma unroll
    for (int w = 1; w < NW; ++w) mx = fmaxf(mx, s_max[w]);

    // ---- P2: value-owner extracts 8 slots (cf b64); ONE packed u64 atomicAdd per item
    //          delivers bucket count AND fixed-point exp total; psum of kept preds ----
    u64 own[8]; float e8[8];
    u32 keptmask = 0;
    float psum = 0.f;
    #pragma unroll
    for (int i = 0; i < 8; ++i) {
        const u64 x = B[(i<<9)+tid];                    // = B[TP(8*tid+i)]
        own[i] = x;
        if (x != ~0ull) {
            keptmask |= 1u << i;
            const float pd = h2f((u16)(x & 0xFFFFu));
            psum += pd;
            const float e = __expf(pd - mx);
            e8[i] = e;
            const int b = (int)((x >> 28) & 0xFFFu);
            atomicAdd(&D[TP(b)], (1ull << 44) | (u64)(e * FXSCALE + 0.5f));
        }
    }
    #pragma unroll
    for (int off = 32; off > 0; off >>= 1) psum += __shfl_down(psum, off);
    if (lane == 0) s_ps[wave] = psum;
    __syncthreads();                                    // B3 (extracts + packed counts done)

    // ---- P3: ONE u64 exclusive scan (8/thread, TP) -> bases (hi44) and S_excl (lo44) ----
    u64 d8[8], lsum = 0ull;
    #pragma unroll
    for (int i = 0; i < 8; ++i) { d8[i] = D[(i<<9)+tid]; lsum += d8[i]; }
    u64 xsu = lsum;
    #pragma unroll
    for (int off = 1; off < 64; off <<= 1) { const u64 y = __shfl_up(xsu, off); if (lane >= off) xsu += y; }
    if (lane == 63) s_sc[wave] = xsu;
    __syncthreads();                                    // B4

    u64 runp = xsu - lsum, grand = 0ull;
    #pragma unroll
    for (int w = 0; w < NW; ++w) { const u64 t = s_sc[w]; if (w < wave) runp += t; grand += t; }
    const u32 K = (u32)(grand >> 44);
    #pragma unroll
    for (int i = 0; i < 8; ++i) {
        Cc[(i<<9)+tid] = (u32)(runp >> 44);                                   // bucket base
        Sf[(i<<9)+tid] = __float_as_uint((float)(runp & TOTMASK) * (1.0f / FXSCALE)); // S_excl
        runp += d8[i];
    }
    __syncthreads();                                    // B5 (bases + S live; packed D dead)

    // ---- P5: scatter entries (rt24|j13|exph16) by atomic arrival; cursor IS base array ----
    #pragma unroll
    for (int i = 0; i < 8; ++i) {
        if (keptmask & (1u << i)) {
            const u64 x = own[i];
            const u32 rt24 = (u32)((x >> 16) & 0xFFFFFFu);
            const u32 j    = (u32)((x >> 40) & 0x1FFFu);
            const u32 pos  = atomicAdd(&Cc[TP((int)(rt24 >> 12))], 1u);
            B[TP((int)pos)] = ((u64)rt24 << 29) | ((u64)j << 16) | (u64)f2h(e8[i]);
        }
    }
    __syncthreads();                                    // B6 (entries in B; Cc[b] = end of b)

    // ---- P6: per-ENTRY pass (thread owns 8 consecutive sorted positions -> correlated
    //          span lengths within wave): within-bucket inclusive prefix + log ----
    double logacc = 0.0;
    #pragma unroll
    for (int i = 0; i < 8; ++i) {
        const u32 p = (u32)(8 * tid + i);
        if (p < K) {
            const u64 x = B[(i<<9)+tid];                // = B[TP(p)]
            const u64 ku = x >> 16;                     // 37-bit unique key (rt24|j13)
            const int b  = (int)(x >> 41);
            const u32 start = b ? Cc[TP(b - 1)] : 0u;
            const u32 end   = Cc[TP(b)];
            double dsm = 0.0;
            for (u32 q = start; q < end; ++q) {
                const u64 y = B[TP((int)q)];
                if ((y >> 16) <= ku) dsm += (double)h2f((u16)(y & 0xFFFFu));
            }
            const float S = __uint_as_float(Sf[TP(b)]);
            logacc += (double)__logf(S + (float)dsm + EPSF);
        }
    }
    #pragma unroll
    for (int off = 32; off > 0; off >>= 1) logacc += __shfl_down(logacc, off);
    if (lane == 0) s_lg[wave] = logacc;
    __syncthreads();                                    // B7

    if (tid == 0) {
        double lt = 0.0; float pt = 0.f;
        #pragma unroll
        for (int w = 0; w < NW; ++w) { lt += s_lg[w]; pt += s_ps[w]; }
        row_out[row] = (float)(lt - (double)pt + (double)((float)K * mx));
    }
}

__global__ __launch_bounds__(256) void listmle_finalize(
    const float* __restrict__ row_out, float* __restrict__ out)
{
    __shared__ double red_d[4];
    const int tid = threadIdx.x;
    const int lane = tid & 63, wave = tid >> 6;
    double acc = 0.0;
    for (int r = tid; r < MROWS; r += 256) acc += (double)row_out[r];
    #pragma unroll
    for (int off = 32; off > 0; off >>= 1) acc += __shfl_down(acc, off);
    if (lane == 0) red_d[wave] = acc;
    __syncthreads();
    if (tid == 0) {
        double tot = 0.0;
        for (int w = 0; w < 4; ++w) tot += red_d[w];
        out[0] = (float)(tot / (double)MROWS);
    }
}

extern "C" void kernel_launch(void* const* d_in, const int* in_sizes, int n_in,
                              void* d_out, int out_size, void* d_ws, size_t ws_size,
                              hipStream_t stream) {
    const float* outputs = (const float*)d_in[0];
    const float* runtime = (const float*)d_in[1];
    const int*   idxs    = (const int*)d_in[2];
    float* out = (float*)d_out;
    float* ws  = (float*)d_ws;

    listmle_row_kernel<<<MROWS, BLOCK, 0, stream>>>(outputs, runtime, idxs, ws);
    listmle_finalize<<<1, 256, 0, stream>>>(ws, out);
}